// Round 1
// baseline (2229.352 us; speedup 1.0000x reference)
//
#include <hip/hip_runtime.h>
#include <hip/hip_bf16.h>

#define T_TOK 16384
#define CDIM  1024
#define ENUM_ 8
#define INTER_ 2730
#define IPAD  2752      // INTER padded to x64
#define NGU   5460
#define NGUPAD 5504     // 2*IPAD: [g | u] each padded to 2752
#define CAP   2560

typedef __attribute__((ext_vector_type(8))) short short8;
typedef __attribute__((ext_vector_type(4))) float f32x4;
typedef unsigned long long u64;
typedef unsigned int u32;

static __device__ __forceinline__ ushort f2bf(float f){
  u32 u = __float_as_uint(f);
  u32 r = u + 0x7FFFu + ((u >> 16) & 1u);
  return (ushort)(r >> 16);
}

// ---------- conversions ----------
__global__ void k_cvt_x(const float* __restrict__ x, ushort* __restrict__ xb){
  int i = blockIdx.x*256 + threadIdx.x;
  float4 v = ((const float4*)x)[i];
  ushort4 o;
  o.x = f2bf(v.x); o.y = f2bf(v.y); o.z = f2bf(v.z); o.w = f2bf(v.w);
  ((ushort4*)xb)[i] = o;
}

// wgu [E][1024][5460] f32  ->  wguT [E][5504][1024] bf16 (transposed, g|u re-based, pads zero)
__global__ void k_tr_wgu(const float* __restrict__ wgu, ushort* __restrict__ wguT){
  __shared__ float tile[32][33];
  const int e = blockIdx.z;
  const int k0 = blockIdx.x*32, n0 = blockIdx.y*32;
  const float* src = wgu + (size_t)e*CDIM*NGU;
  ushort* dst = wguT + (size_t)e*NGUPAD*CDIM;
  const int tx = threadIdx.x, ty = threadIdx.y;
  #pragma unroll
  for (int r = ty; r < 32; r += 8){
    int n = n0 + tx;
    int j = (n < IPAD) ? n : n - (IPAD - INTER_);   // u half shifts back by 22
    bool valid = (n < INTER_) || (n >= IPAD && j < NGU);
    tile[r][tx] = valid ? src[(size_t)(k0 + r)*NGU + j] : 0.f;
  }
  __syncthreads();
  #pragma unroll
  for (int r = ty; r < 32; r += 8)
    dst[(size_t)(n0 + r)*CDIM + k0 + tx] = f2bf(tile[tx][r]);
}

// down [E][2730][1024] f32 -> dwT [E][1024][2752] bf16 (transposed, k-pad zero)
__global__ void k_tr_dwn(const float* __restrict__ dw, ushort* __restrict__ dwT){
  __shared__ float tile[32][33];
  const int e = blockIdx.z;
  const int k0 = blockIdx.x*32, n0 = blockIdx.y*32;
  const float* src = dw + (size_t)e*INTER_*CDIM;
  ushort* dst = dwT + (size_t)e*CDIM*IPAD;
  const int tx = threadIdx.x, ty = threadIdx.y;
  #pragma unroll
  for (int r = ty; r < 32; r += 8){
    int k = k0 + r;
    tile[r][tx] = (k < INTER_) ? src[(size_t)k*CDIM + n0 + tx] : 0.f;
  }
  __syncthreads();
  #pragma unroll
  for (int r = ty; r < 32; r += 8)
    dst[(size_t)(n0 + r)*IPAD + k0 + tx] = f2bf(tile[tx][r]);
}

// ---------- gating ----------
__global__ void k_cond(const float* __restrict__ cond, const float* __restrict__ gate_w,
                       float* __restrict__ condlog){
  const int b = blockIdx.x;
  const int wave = threadIdx.x >> 6, lane = threadIdx.x & 63;
  float a0 = 0.f, a1 = 0.f;
  for (int c = lane; c < CDIM; c += 64){
    float cv = cond[(size_t)b*CDIM + c];
    const float* g = gate_w + (size_t)(CDIM + c)*8;
    a0 += cv * g[2*wave]; a1 += cv * g[2*wave + 1];
  }
  #pragma unroll
  for (int off = 32; off; off >>= 1){
    a0 += __shfl_down(a0, off, 64);
    a1 += __shfl_down(a1, off, 64);
  }
  if (lane == 0){
    condlog[b*8 + 2*wave]     = a0;
    condlog[b*8 + 2*wave + 1] = a1;
  }
}

__global__ void k_gate(const float* __restrict__ x, const float* __restrict__ gate_w,
                       const float* __restrict__ condlog, const float* __restrict__ snr,
                       u32* __restrict__ cnt, u64* __restrict__ entries){
  const int wave = threadIdx.x >> 6, lane = threadIdx.x & 63;
  const int t = blockIdx.x*4 + wave;
  const int b = t >> 12;                       // N = 4096 tokens/batch
  float acc[8] = {0,0,0,0,0,0,0,0};
  const float* xr = x + (size_t)t*CDIM;
  for (int c = lane; c < CDIM; c += 64){
    float xv = xr[c];
    const float* g = gate_w + (size_t)c*8;
    #pragma unroll
    for (int e = 0; e < 8; ++e) acc[e] += xv * g[e];
  }
  #pragma unroll
  for (int e = 0; e < 8; ++e)
    #pragma unroll
    for (int off = 32; off; off >>= 1)
      acc[e] += __shfl_down(acc[e], off, 64);
  if (lane == 0){
    bool hn = snr[b] < 0.5f;
    float lg[8];
    #pragma unroll
    for (int e = 0; e < 8; ++e) lg[e] = acc[e] + condlog[b*8 + e];
    float mx = -1e30f;
    #pragma unroll
    for (int e = 0; e < 8; ++e) if (!(hn && e >= 2) && lg[e] > mx) mx = lg[e];
    float p[8]; float s = 0.f;
    #pragma unroll
    for (int e = 0; e < 8; ++e){ p[e] = (hn && e >= 2) ? 0.f : expf(lg[e] - mx); s += p[e]; }
    float inv = 1.f / s;
    #pragma unroll
    for (int e = 0; e < 8; ++e) p[e] *= inv;
    int i0 = 0;
    #pragma unroll
    for (int e = 1; e < 8; ++e) if (p[e] > p[i0]) i0 = e;   // first-occurrence argmax
    int i1 = -1; float pv1 = -1.f;
    #pragma unroll
    for (int e = 0; e < 8; ++e) if (e != i0 && p[e] > pv1){ pv1 = p[e]; i1 = e; }
    float v0 = p[i0], v1 = pv1;
    float den = fmaxf(v0 + v1, 1e-12f);
    v0 /= den; v1 /= den;
    u32 flat0 = (u32)(t*2);
    u32 pos0 = atomicAdd(&cnt[i0], 1u);
    entries[(size_t)i0*T_TOK + pos0] =
        ((u64)__float_as_uint(v0) << 32) | (u64)(0xFFFFFFFFu - flat0);
    u32 pos1 = atomicAdd(&cnt[i1], 1u);
    entries[(size_t)i1*T_TOK + pos1] =
        ((u64)__float_as_uint(v1) << 32) | (u64)(0xFFFFFFFFu - (flat0 + 1u));
  }
}

// ---------- capacity selection (exact jax.lax.top_k semantics via unique 64b keys) ----------
__global__ void k_select(const u32* __restrict__ cnt, const u64* __restrict__ entries,
                         u64* __restrict__ thresh){
  const int e = blockIdx.x;
  const int n = (int)cnt[e];
  if (n <= CAP){ if (threadIdx.x == 0) thresh[e] = 0ull; return; }
  const u64* keys = entries + (size_t)e*T_TOK;
  __shared__ u32 hist[256];
  __shared__ u64 spfx;
  __shared__ int srem;
  u64 prefix = 0, pmask = 0;
  int rem = CAP;
  for (int d = 7; d >= 0; --d){
    const int sh = d*8;
    hist[threadIdx.x] = 0;
    __syncthreads();
    for (int i = threadIdx.x; i < n; i += 256){
      u64 k = keys[i];
      if ((k & pmask) == prefix)
        atomicAdd(&hist[(u32)((k >> sh) & 0xFFull)], 1u);
    }
    __syncthreads();
    if (threadIdx.x == 0){
      int c = 0, chosen = 0, nr = rem;
      for (int v = 255; v >= 0; --v){
        int nc = c + (int)hist[v];
        if (nc >= rem){ chosen = v; nr = rem - c; break; }
        c = nc;
      }
      spfx = prefix | ((u64)(u32)chosen << sh);
      srem = nr;
    }
    __syncthreads();
    prefix = spfx; rem = srem; pmask |= (0xFFull << sh);
  }
  if (threadIdx.x == 0) thresh[e] = prefix;   // exact CAP-th largest key
}

__global__ void k_compact(const u32* __restrict__ cnt, const u64* __restrict__ entries,
                          const u64* __restrict__ thresh, u32* __restrict__ mcnt,
                          int* __restrict__ tokbuf, float* __restrict__ wgtbuf){
  const int e = blockIdx.y;
  const int n = (int)cnt[e];
  const u64 th = thresh[e];
  const u64* keys = entries + (size_t)e*T_TOK;
  for (int i = blockIdx.x*256 + threadIdx.x; i < n; i += gridDim.x*256){
    u64 k = keys[i];
    if (k >= th){
      u32 pos = atomicAdd(&mcnt[e], 1u);
      u32 flat = 0xFFFFFFFFu - (u32)(k & 0xFFFFFFFFull);
      tokbuf[(size_t)e*CAP + pos] = (int)(flat >> 1);
      wgtbuf[(size_t)e*CAP + pos] = __uint_as_float((u32)(k >> 32));
    }
  }
}

// ---------- expert GEMMs ----------
// GEMM1: h[m][j] = silu(Xg)*Xu,  A = gathered x_bf16 rows, B = wguT (n-major)
__global__ __launch_bounds__(256) void k_gemm1(
    const ushort* __restrict__ xb, const ushort* __restrict__ wguT,
    const int* __restrict__ tok, const u32* __restrict__ mptr,
    ushort* __restrict__ h){
  const int m_e = (int)*mptr;
  const int m0 = blockIdx.x * 128;
  if (m0 >= m_e) return;
  const int j0 = blockIdx.y * 64;
  __shared__ ushort As[128][40];
  __shared__ ushort Bs[2][64][40];
  const int tid = threadIdx.x;
  const int lane = tid & 63, wave = tid >> 6;
  const int wm = wave >> 1, wn = wave & 1;
  const int lm = lane & 15, quad = lane >> 4;
  f32x4 accg[4][2], accu[4][2];
  #pragma unroll
  for (int i = 0; i < 4; ++i)
    #pragma unroll
    for (int j = 0; j < 2; ++j){
      accg[i][j] = (f32x4){0.f,0.f,0.f,0.f};
      accu[i][j] = (f32x4){0.f,0.f,0.f,0.f};
    }
  int arow[2], akc[2], atk[2];
  #pragma unroll
  for (int tt = 0; tt < 2; ++tt){
    int cid = tid + tt*256;
    arow[tt] = cid >> 2; akc[tt] = (cid & 3) * 8;
    int gr = m0 + arow[tt];
    atk[tt] = (gr < m_e) ? tok[gr] : -1;
  }
  const int nb = tid >> 2, kcb = (tid & 3) * 8;
  const ushort* bsrc0 = wguT + (size_t)(j0 + nb)*CDIM + kcb;
  const ushort* bsrc1 = wguT + (size_t)(IPAD + j0 + nb)*CDIM + kcb;

  for (int k0 = 0; k0 < CDIM; k0 += 32){
    #pragma unroll
    for (int tt = 0; tt < 2; ++tt){
      int4 v = make_int4(0,0,0,0);
      if (atk[tt] >= 0) v = *(const int4*)(xb + (size_t)atk[tt]*CDIM + k0 + akc[tt]);
      *(int4*)&As[arow[tt]][akc[tt]] = v;
    }
    *(int4*)&Bs[0][nb][kcb] = *(const int4*)(bsrc0 + k0);
    *(int4*)&Bs[1][nb][kcb] = *(const int4*)(bsrc1 + k0);
    __syncthreads();
    short8 a[4], bg[2], bu[2];
    #pragma unroll
    for (int mt = 0; mt < 4; ++mt) a[mt] = *(const short8*)&As[wm*64 + mt*16 + lm][quad*8];
    #pragma unroll
    for (int nt = 0; nt < 2; ++nt){
      bg[nt] = *(const short8*)&Bs[0][wn*32 + nt*16 + lm][quad*8];
      bu[nt] = *(const short8*)&Bs[1][wn*32 + nt*16 + lm][quad*8];
    }
    #pragma unroll
    for (int mt = 0; mt < 4; ++mt)
      #pragma unroll
      for (int nt = 0; nt < 2; ++nt){
        accg[mt][nt] = __builtin_amdgcn_mfma_f32_16x16x32_bf16(a[mt], bg[nt], accg[mt][nt], 0, 0, 0);
        accu[mt][nt] = __builtin_amdgcn_mfma_f32_16x16x32_bf16(a[mt], bu[nt], accu[mt][nt], 0, 0, 0);
      }
    __syncthreads();
  }
  #pragma unroll
  for (int mt = 0; mt < 4; ++mt)
    #pragma unroll
    for (int nt = 0; nt < 2; ++nt)
      #pragma unroll
      for (int r = 0; r < 4; ++r){
        int row = m0 + wm*64 + mt*16 + quad*4 + r;   // C/D: row = quad*4+reg
        int col = j0 + wn*32 + nt*16 + lm;           //      col = lane&15
        float g = accg[mt][nt][r];
        float uu = accu[mt][nt][r];
        float sg = g / (1.f + __expf(-g));
        h[(size_t)row*IPAD + col] = f2bf(sg * uu);
      }
}

// GEMM2: out[tok[m]] += w[m] * (h @ down),  B = dwT (n-major)
__global__ __launch_bounds__(256) void k_gemm2(
    const ushort* __restrict__ h, const ushort* __restrict__ dwT,
    const int* __restrict__ tok, const float* __restrict__ wgt,
    const u32* __restrict__ mptr, float* __restrict__ out){
  const int m_e = (int)*mptr;
  const int m0 = blockIdx.x * 128;
  if (m0 >= m_e) return;
  const int n0 = blockIdx.y * 64;
  __shared__ ushort As[128][40];
  __shared__ ushort Bs[64][40];
  const int tid = threadIdx.x;
  const int lane = tid & 63, wave = tid >> 6;
  const int wm = wave >> 1, wn = wave & 1;
  const int lm = lane & 15, quad = lane >> 4;
  f32x4 acc[4][2];
  #pragma unroll
  for (int i = 0; i < 4; ++i)
    #pragma unroll
    for (int j = 0; j < 2; ++j) acc[i][j] = (f32x4){0.f,0.f,0.f,0.f};
  int arow[2], akc[2];
  #pragma unroll
  for (int tt = 0; tt < 2; ++tt){
    int cid = tid + tt*256;
    arow[tt] = cid >> 2; akc[tt] = (cid & 3) * 8;
  }
  const int nb = tid >> 2, kcb = (tid & 3) * 8;
  const ushort* bsrc = dwT + (size_t)(n0 + nb)*IPAD + kcb;

  for (int k0 = 0; k0 < IPAD; k0 += 32){
    #pragma unroll
    for (int tt = 0; tt < 2; ++tt)
      *(int4*)&As[arow[tt]][akc[tt]] =
          *(const int4*)(h + (size_t)(m0 + arow[tt])*IPAD + k0 + akc[tt]);
    *(int4*)&Bs[nb][kcb] = *(const int4*)(bsrc + k0);
    __syncthreads();
    short8 a[4], b[2];
    #pragma unroll
    for (int mt = 0; mt < 4; ++mt) a[mt] = *(const short8*)&As[wm*64 + mt*16 + lm][quad*8];
    #pragma unroll
    for (int nt = 0; nt < 2; ++nt) b[nt] = *(const short8*)&Bs[wn*32 + nt*16 + lm][quad*8];
    #pragma unroll
    for (int mt = 0; mt < 4; ++mt)
      #pragma unroll
      for (int nt = 0; nt < 2; ++nt)
        acc[mt][nt] = __builtin_amdgcn_mfma_f32_16x16x32_bf16(a[mt], b[nt], acc[mt][nt], 0, 0, 0);
    __syncthreads();
  }
  #pragma unroll
  for (int mt = 0; mt < 4; ++mt)
    #pragma unroll
    for (int nt = 0; nt < 2; ++nt)
      #pragma unroll
      for (int r = 0; r < 4; ++r){
        int row = m0 + wm*64 + mt*16 + quad*4 + r;
        int col = n0 + wn*32 + nt*16 + lm;
        if (row < m_e){
          float w = wgt[row];
          atomicAdd(&out[(size_t)tok[row]*CDIM + col], w * acc[mt][nt][r]);
        }
      }
}

extern "C" void kernel_launch(void* const* d_in, const int* in_sizes, int n_in,
                              void* d_out, int out_size, void* d_ws, size_t ws_size,
                              hipStream_t stream){
  const float* x      = (const float*)d_in[0];
  const float* cond   = (const float*)d_in[1];
  const float* snr    = (const float*)d_in[2];
  const float* gate_w = (const float*)d_in[3];
  const float* wgu    = (const float*)d_in[4];
  const float* wdn    = (const float*)d_in[5];
  float* out = (float*)d_out;
  (void)in_sizes; (void)n_in; (void)ws_size;

  char* ws = (char*)d_ws;
  size_t off = 0;
  auto take = [&](size_t bytes) -> char* {
    char* p = ws + off;
    off += (bytes + 255) & ~(size_t)255;
    return p;
  };
  u32* ctrl     = (u32*)take(256);
  u32* cnt      = ctrl;                      // 8 x u32
  u32* mcnt     = ctrl + 8;                  // 8 x u32
  float* condlog = (float*)(ctrl + 16);      // 32 x f32 @ byte 64
  u64* thresh   = (u64*)((char*)ctrl + 192); // 8 x u64
  u64* entries  = (u64*)take((size_t)ENUM_*T_TOK*8);
  int* tokbuf   = (int*)take((size_t)ENUM_*CAP*4);
  float* wgtbuf = (float*)take((size_t)ENUM_*CAP*4);
  ushort* xb    = (ushort*)take((size_t)T_TOK*CDIM*2);
  ushort* wguT  = (ushort*)take((size_t)ENUM_*NGUPAD*CDIM*2);
  ushort* dwT   = (ushort*)take((size_t)ENUM_*CDIM*IPAD*2);
  ushort* hbuf  = (ushort*)take((size_t)CAP*IPAD*2);

  hipMemsetAsync(ctrl, 0, 64, stream);
  hipMemsetAsync(out, 0, (size_t)out_size*sizeof(float), stream);

  k_cvt_x<<<T_TOK*CDIM/1024, 256, 0, stream>>>(x, xb);
  k_tr_wgu<<<dim3(CDIM/32, NGUPAD/32, ENUM_), dim3(32,8), 0, stream>>>(wgu, wguT);
  k_tr_dwn<<<dim3(IPAD/32, CDIM/32, ENUM_), dim3(32,8), 0, stream>>>(wdn, dwT);
  k_cond<<<4, 256, 0, stream>>>(cond, gate_w, condlog);
  k_gate<<<T_TOK/4, 256, 0, stream>>>(x, gate_w, condlog, snr, cnt, entries);
  k_select<<<ENUM_, 256, 0, stream>>>(cnt, entries, thresh);
  k_compact<<<dim3(64, ENUM_), 256, 0, stream>>>(cnt, entries, thresh, mcnt, tokbuf, wgtbuf);
  for (int e = 0; e < ENUM_; ++e){
    k_gemm1<<<dim3(CAP/128, IPAD/64), 256, 0, stream>>>(
        xb, wguT + (size_t)e*NGUPAD*CDIM, tokbuf + (size_t)e*CAP, mcnt + e, hbuf);
    k_gemm2<<<dim3(CAP/128, CDIM/64), 256, 0, stream>>>(
        hbuf, dwT + (size_t)e*CDIM*IPAD, tokbuf + (size_t)e*CAP,
        wgtbuf + (size_t)e*CAP, mcnt + e, out);
  }
}

// Round 2
// 1577.502 us; speedup vs baseline: 1.4132x; 1.4132x over previous
//
#include <hip/hip_runtime.h>
#include <hip/hip_bf16.h>
#include <stdint.h>

#define T_TOK 16384
#define CDIM  1024
#define ENUM_ 8
#define INTER_ 2730
#define IPAD  2752      // INTER padded to x64
#define NGU   5460
#define NGUPAD 5504     // 2*IPAD: [g | u] each padded to 2752
#define CAP   2560
#define EGRP  4         // experts per GEMM dispatch (blockIdx.z)

typedef __attribute__((ext_vector_type(8))) short short8;
typedef __attribute__((ext_vector_type(4))) float f32x4;
typedef unsigned long long u64;
typedef unsigned int u32;

static __device__ __forceinline__ ushort f2bf(float f){
  u32 u = __float_as_uint(f);
  u32 r = u + 0x7FFFu + ((u >> 16) & 1u);
  return (ushort)(r >> 16);
}

// async global->LDS, 16B per lane. LDS dest = wave-uniform base + lane*16,
// so pass base + lane*16 consistently (linear, unpadded LDS tiles only).
static __device__ __forceinline__ void glds16(const void* g, void* l){
  __builtin_amdgcn_global_load_lds(
      (const __attribute__((address_space(1))) void*)g,
      (__attribute__((address_space(3))) void*)l, 16, 0, 0);
}

// ---------- weight transposes (unchanged; revisit if they hit top-5) ----------
__global__ void k_tr_wgu(const float* __restrict__ wgu, ushort* __restrict__ wguT){
  __shared__ float tile[32][33];
  const int e = blockIdx.z;
  const int k0 = blockIdx.x*32, n0 = blockIdx.y*32;
  const float* src = wgu + (size_t)e*CDIM*NGU;
  ushort* dst = wguT + (size_t)e*NGUPAD*CDIM;
  const int tx = threadIdx.x, ty = threadIdx.y;
  #pragma unroll
  for (int r = ty; r < 32; r += 8){
    int n = n0 + tx;
    int j = (n < IPAD) ? n : n - (IPAD - INTER_);
    bool valid = (n < INTER_) || (n >= IPAD && j < NGU);
    tile[r][tx] = valid ? src[(size_t)(k0 + r)*NGU + j] : 0.f;
  }
  __syncthreads();
  #pragma unroll
  for (int r = ty; r < 32; r += 8)
    dst[(size_t)(n0 + r)*CDIM + k0 + tx] = f2bf(tile[tx][r]);
}

__global__ void k_tr_dwn(const float* __restrict__ dw, ushort* __restrict__ dwT){
  __shared__ float tile[32][33];
  const int e = blockIdx.z;
  const int k0 = blockIdx.x*32, n0 = blockIdx.y*32;
  const float* src = dw + (size_t)e*INTER_*CDIM;
  ushort* dst = dwT + (size_t)e*CDIM*IPAD;
  const int tx = threadIdx.x, ty = threadIdx.y;
  #pragma unroll
  for (int r = ty; r < 32; r += 8){
    int k = k0 + r;
    tile[r][tx] = (k < INTER_) ? src[(size_t)k*CDIM + n0 + tx] : 0.f;
  }
  __syncthreads();
  #pragma unroll
  for (int r = ty; r < 32; r += 8)
    dst[(size_t)(n0 + r)*IPAD + k0 + tx] = f2bf(tile[tx][r]);
}

// ---------- gating ----------
__global__ void k_cond(const float* __restrict__ cond, const float* __restrict__ gate_w,
                       float* __restrict__ condlog){
  const int b = blockIdx.x;
  const int wave = threadIdx.x >> 6, lane = threadIdx.x & 63;
  float a0 = 0.f, a1 = 0.f;
  for (int c = lane; c < CDIM; c += 64){
    float cv = cond[(size_t)b*CDIM + c];
    const float* g = gate_w + (size_t)(CDIM + c)*8;
    a0 += cv * g[2*wave]; a1 += cv * g[2*wave + 1];
  }
  #pragma unroll
  for (int off = 32; off; off >>= 1){
    a0 += __shfl_down(a0, off, 64);
    a1 += __shfl_down(a1, off, 64);
  }
  if (lane == 0){
    condlog[b*8 + 2*wave]     = a0;
    condlog[b*8 + 2*wave + 1] = a1;
  }
}

// Fused: gate logits (f32, register-cached gate_w) + x->bf16 conversion.
// Lane l owns c in [16l, 16l+16): its 128 gate weights live in 128 VGPRs.
__global__ __launch_bounds__(256) void k_gate(
    const float* __restrict__ x, const float* __restrict__ gate_w,
    const float* __restrict__ condlog, const float* __restrict__ snr,
    u32* __restrict__ cnt, u64* __restrict__ entries, ushort* __restrict__ xb){
  const int wave = threadIdx.x >> 6, lane = threadIdx.x & 63;
  float gw[128];
  #pragma unroll
  for (int rr = 0; rr < 16; ++rr){
    float4 v0 = *(const float4*)(gate_w + (size_t)(lane*16 + rr)*8);
    float4 v1 = *(const float4*)(gate_w + (size_t)(lane*16 + rr)*8 + 4);
    gw[rr*8+0]=v0.x; gw[rr*8+1]=v0.y; gw[rr*8+2]=v0.z; gw[rr*8+3]=v0.w;
    gw[rr*8+4]=v1.x; gw[rr*8+5]=v1.y; gw[rr*8+6]=v1.z; gw[rr*8+7]=v1.w;
  }
  const int tbase = blockIdx.x*16 + wave*4;
  #pragma unroll 1
  for (int it = 0; it < 4; ++it){
    const int t = tbase + it;
    const int b = t >> 12;          // N = 4096 tokens/batch
    float acc[8] = {0,0,0,0,0,0,0,0};
    #pragma unroll
    for (int p = 0; p < 4; ++p){
      const int c = lane*16 + p*4;
      float4 xv = *(const float4*)(x + (size_t)t*CDIM + c);
      ushort4 o;
      o.x = f2bf(xv.x); o.y = f2bf(xv.y); o.z = f2bf(xv.z); o.w = f2bf(xv.w);
      *(ushort4*)(xb + (size_t)t*CDIM + c) = o;
      float xa[4] = {xv.x, xv.y, xv.z, xv.w};
      #pragma unroll
      for (int j = 0; j < 4; ++j)
        #pragma unroll
        for (int e = 0; e < 8; ++e)
          acc[e] += xa[j] * gw[(p*4 + j)*8 + e];
    }
    #pragma unroll
    for (int e = 0; e < 8; ++e)
      #pragma unroll
      for (int off = 32; off; off >>= 1)
        acc[e] += __shfl_down(acc[e], off, 64);
    if (lane == 0){
      bool hn = snr[b] < 0.5f;
      float lg[8];
      #pragma unroll
      for (int e = 0; e < 8; ++e) lg[e] = acc[e] + condlog[b*8 + e];
      float mx = -1e30f;
      #pragma unroll
      for (int e = 0; e < 8; ++e) if (!(hn && e >= 2) && lg[e] > mx) mx = lg[e];
      float p[8]; float s = 0.f;
      #pragma unroll
      for (int e = 0; e < 8; ++e){ p[e] = (hn && e >= 2) ? 0.f : expf(lg[e] - mx); s += p[e]; }
      float inv = 1.f / s;
      #pragma unroll
      for (int e = 0; e < 8; ++e) p[e] *= inv;
      int i0 = 0;
      #pragma unroll
      for (int e = 1; e < 8; ++e) if (p[e] > p[i0]) i0 = e;
      int i1 = -1; float pv1 = -1.f;
      #pragma unroll
      for (int e = 0; e < 8; ++e) if (e != i0 && p[e] > pv1){ pv1 = p[e]; i1 = e; }
      float v0 = p[i0], v1 = pv1;
      float den = fmaxf(v0 + v1, 1e-12f);
      v0 /= den; v1 /= den;
      u32 flat0 = (u32)(t*2);
      u32 pos0 = atomicAdd(&cnt[i0], 1u);
      entries[(size_t)i0*T_TOK + pos0] =
          ((u64)__float_as_uint(v0) << 32) | (u64)(0xFFFFFFFFu - flat0);
      u32 pos1 = atomicAdd(&cnt[i1], 1u);
      entries[(size_t)i1*T_TOK + pos1] =
          ((u64)__float_as_uint(v1) << 32) | (u64)(0xFFFFFFFFu - (flat0 + 1u));
    }
  }
}

// ---------- capacity selection (exact top-k via unique 64b keys) ----------
__global__ void k_select(const u32* __restrict__ cnt, const u64* __restrict__ entries,
                         u64* __restrict__ thresh){
  const int e = blockIdx.x;
  const int n = (int)cnt[e];
  if (n <= CAP){ if (threadIdx.x == 0) thresh[e] = 0ull; return; }
  const u64* keys = entries + (size_t)e*T_TOK;
  __shared__ u32 hist[256];
  __shared__ u64 spfx;
  __shared__ int srem;
  u64 prefix = 0, pmask = 0;
  int rem = CAP;
  for (int d = 7; d >= 0; --d){
    const int sh = d*8;
    hist[threadIdx.x] = 0;
    __syncthreads();
    for (int i = threadIdx.x; i < n; i += 256){
      u64 k = keys[i];
      if ((k & pmask) == prefix)
        atomicAdd(&hist[(u32)((k >> sh) & 0xFFull)], 1u);
    }
    __syncthreads();
    if (threadIdx.x == 0){
      int c = 0, chosen = 0, nr = rem;
      for (int v = 255; v >= 0; --v){
        int nc = c + (int)hist[v];
        if (nc >= rem){ chosen = v; nr = rem - c; break; }
        c = nc;
      }
      spfx = prefix | ((u64)(u32)chosen << sh);
      srem = nr;
    }
    __syncthreads();
    prefix = spfx; rem = srem; pmask |= (0xFFull << sh);
  }
  if (threadIdx.x == 0) thresh[e] = prefix;
}

__global__ void k_compact(const u32* __restrict__ cnt, const u64* __restrict__ entries,
                          const u64* __restrict__ thresh, u32* __restrict__ mcnt,
                          int* __restrict__ tokbuf, float* __restrict__ wgtbuf){
  const int e = blockIdx.y;
  const int n = (int)cnt[e];
  const u64 th = thresh[e];
  const u64* keys = entries + (size_t)e*T_TOK;
  for (int i = blockIdx.x*256 + threadIdx.x; i < n; i += gridDim.x*256){
    u64 k = keys[i];
    if (k >= th){
      u32 pos = atomicAdd(&mcnt[e], 1u);
      u32 flat = 0xFFFFFFFFu - (u32)(k & 0xFFFFFFFFull);
      tokbuf[(size_t)e*CAP + pos] = (int)(flat >> 1);
      wgtbuf[(size_t)e*CAP + pos] = __uint_as_float((u32)(k >> 32));
    }
  }
}

// ---------- expert GEMMs, m97 structure ----------
// GEMM1: per expert (z), tile M128 x (64 g-cols + 64 u-cols), BK=32,
// global_load_lds staging, [glds; bar; ds_read; bar; mfma] K-loop.
__global__ __launch_bounds__(256) void k_gemm1(
    const ushort* __restrict__ xb, const ushort* __restrict__ wguT_g,
    const int* __restrict__ tok_g, const u32* __restrict__ mcnt_g,
    ushort* __restrict__ h_g){
  const int z = blockIdx.z;
  const int m_e = (int)mcnt_g[z];
  const int m0 = blockIdx.x * 128;
  if (m0 >= m_e) return;
  const ushort* wguT = wguT_g + (size_t)z*NGUPAD*CDIM;
  const int* tok = tok_g + (size_t)z*CAP;
  ushort* h = h_g + (size_t)z*CAP*IPAD;
  const int j0 = blockIdx.y * 64;

  __shared__ ushort As[128*32];
  __shared__ ushort Bg[64*32];
  __shared__ ushort Bu[64*32];
  const int tid = threadIdx.x;
  const int lane = tid & 63, wave = tid >> 6;
  const int wm = wave >> 1, wn = wave & 1;
  const int lm = lane & 15, quad = lane >> 4;

  // staging addresses (rows fixed per thread; padded slots use tok=0, wgt=0)
  const int af0 = tid*8, af1 = tid*8 + 2048;
  const ushort* ag0 = xb + (size_t)tok[m0 + (af0 >> 5)]*CDIM + (af0 & 31);
  const ushort* ag1 = xb + (size_t)tok[m0 + (af1 >> 5)]*CDIM + (af1 & 31);
  const int br = tid >> 2, bc = (tid & 3)*8;
  const ushort* bgp = wguT + (size_t)(j0 + br)*CDIM + bc;
  const ushort* bup = wguT + (size_t)(IPAD + j0 + br)*CDIM + bc;

  f32x4 accg[4][2], accu[4][2];
  #pragma unroll
  for (int i = 0; i < 4; ++i)
    #pragma unroll
    for (int j = 0; j < 2; ++j){
      accg[i][j] = (f32x4){0.f,0.f,0.f,0.f};
      accu[i][j] = (f32x4){0.f,0.f,0.f,0.f};
    }

  for (int k0 = 0; k0 < CDIM; k0 += 32){
    glds16(ag0 + k0, As + af0);
    glds16(ag1 + k0, As + af1);
    glds16(bgp + k0, Bg + tid*8);
    glds16(bup + k0, Bu + tid*8);
    __syncthreads();                        // tile ready (vmcnt drain)
    short8 a[4], vg[2], vu[2];
    #pragma unroll
    for (int mt = 0; mt < 4; ++mt)
      a[mt] = *(const short8*)(As + (wm*64 + mt*16 + lm)*32 + quad*8);
    #pragma unroll
    for (int nt = 0; nt < 2; ++nt){
      vg[nt] = *(const short8*)(Bg + (wn*32 + nt*16 + lm)*32 + quad*8);
      vu[nt] = *(const short8*)(Bu + (wn*32 + nt*16 + lm)*32 + quad*8);
    }
    __syncthreads();                        // frags in regs; LDS free for next stage
    #pragma unroll
    for (int mt = 0; mt < 4; ++mt)
      #pragma unroll
      for (int nt = 0; nt < 2; ++nt){
        accg[mt][nt] = __builtin_amdgcn_mfma_f32_16x16x32_bf16(a[mt], vg[nt], accg[mt][nt], 0, 0, 0);
        accu[mt][nt] = __builtin_amdgcn_mfma_f32_16x16x32_bf16(a[mt], vu[nt], accu[mt][nt], 0, 0, 0);
      }
  }
  #pragma unroll
  for (int mt = 0; mt < 4; ++mt)
    #pragma unroll
    for (int nt = 0; nt < 2; ++nt)
      #pragma unroll
      for (int r = 0; r < 4; ++r){
        int row = m0 + wm*64 + mt*16 + quad*4 + r;   // C/D: row = quad*4 + reg
        int col = j0 + wn*32 + nt*16 + lm;           //      col = lane & 15
        float g = accg[mt][nt][r];
        float uu = accu[mt][nt][r];
        float sg = g / (1.f + __expf(-g));
        h[(size_t)row*IPAD + col] = f2bf(sg * uu);
      }
}

// GEMM2: tile 128x128 over (slots, C), K=IPAD, scatter atomicAdd epilogue.
__global__ __launch_bounds__(256) void k_gemm2(
    const ushort* __restrict__ h_g, const ushort* __restrict__ dwT_g,
    const int* __restrict__ tok_g, const float* __restrict__ wgt_g,
    const u32* __restrict__ mcnt_g, float* __restrict__ out){
  const int z = blockIdx.z;
  const int m_e = (int)mcnt_g[z];
  const int m0 = blockIdx.x * 128;
  if (m0 >= m_e) return;
  const ushort* h = h_g + (size_t)z*CAP*IPAD;
  const ushort* dwT = dwT_g + (size_t)z*CDIM*IPAD;
  const int* tok = tok_g + (size_t)z*CAP;
  const float* wgt = wgt_g + (size_t)z*CAP;
  const int n0 = blockIdx.y * 128;

  __shared__ ushort As[128*32];
  __shared__ ushort Bs[128*32];
  const int tid = threadIdx.x;
  const int lane = tid & 63, wave = tid >> 6;
  const int wm = wave >> 1, wn = wave & 1;
  const int lm = lane & 15, quad = lane >> 4;

  const int af0 = tid*8, af1 = tid*8 + 2048;
  const ushort* ap0 = h + (size_t)(m0 + (af0 >> 5))*IPAD + (af0 & 31);
  const ushort* ap1 = h + (size_t)(m0 + (af1 >> 5))*IPAD + (af1 & 31);
  const ushort* bp0 = dwT + (size_t)(n0 + (af0 >> 5))*IPAD + (af0 & 31);
  const ushort* bp1 = dwT + (size_t)(n0 + (af1 >> 5))*IPAD + (af1 & 31);

  f32x4 acc[4][4];
  #pragma unroll
  for (int i = 0; i < 4; ++i)
    #pragma unroll
    for (int j = 0; j < 4; ++j) acc[i][j] = (f32x4){0.f,0.f,0.f,0.f};

  for (int k0 = 0; k0 < IPAD; k0 += 32){
    glds16(ap0 + k0, As + af0);
    glds16(ap1 + k0, As + af1);
    glds16(bp0 + k0, Bs + af0);
    glds16(bp1 + k0, Bs + af1);
    __syncthreads();
    short8 a[4], b[4];
    #pragma unroll
    for (int mt = 0; mt < 4; ++mt)
      a[mt] = *(const short8*)(As + (wm*64 + mt*16 + lm)*32 + quad*8);
    #pragma unroll
    for (int nt = 0; nt < 4; ++nt)
      b[nt] = *(const short8*)(Bs + (wn*64 + nt*16 + lm)*32 + quad*8);
    __syncthreads();
    #pragma unroll
    for (int mt = 0; mt < 4; ++mt)
      #pragma unroll
      for (int nt = 0; nt < 4; ++nt)
        acc[mt][nt] = __builtin_amdgcn_mfma_f32_16x16x32_bf16(a[mt], b[nt], acc[mt][nt], 0, 0, 0);
  }
  #pragma unroll
  for (int mt = 0; mt < 4; ++mt)
    #pragma unroll
    for (int r = 0; r < 4; ++r){
      int row = m0 + wm*64 + mt*16 + quad*4 + r;
      float w = wgt[row];                       // 0 for padded slots
      float* orow = out + (size_t)tok[row]*CDIM;
      #pragma unroll
      for (int nt = 0; nt < 4; ++nt){
        int col = n0 + wn*64 + nt*16 + lm;
        atomicAdd(orow + col, w * acc[mt][nt][r]);
      }
    }
}

extern "C" void kernel_launch(void* const* d_in, const int* in_sizes, int n_in,
                              void* d_out, int out_size, void* d_ws, size_t ws_size,
                              hipStream_t stream){
  const float* x      = (const float*)d_in[0];
  const float* cond   = (const float*)d_in[1];
  const float* snr    = (const float*)d_in[2];
  const float* gate_w = (const float*)d_in[3];
  const float* wgu    = (const float*)d_in[4];
  const float* wdn    = (const float*)d_in[5];
  float* out = (float*)d_out;
  (void)in_sizes; (void)n_in; (void)ws_size;

  char* ws = (char*)d_ws;
  size_t off = 0;
  auto take = [&](size_t bytes) -> char* {
    char* p = ws + off;
    off += (bytes + 255) & ~(size_t)255;
    return p;
  };
  u32* ctrl     = (u32*)take(256);
  u32* cnt      = ctrl;                      // 8 x u32
  u32* mcnt     = ctrl + 8;                  // 8 x u32
  float* condlog = (float*)(ctrl + 16);      // 32 x f32 @ byte 64
  u64* thresh   = (u64*)((char*)ctrl + 192); // 8 x u64
  u64* entries  = (u64*)take((size_t)ENUM_*T_TOK*8);
  int* tokbuf   = (int*)take((size_t)ENUM_*CAP*4);
  float* wgtbuf = (float*)take((size_t)ENUM_*CAP*4);
  ushort* xb    = (ushort*)take((size_t)T_TOK*CDIM*2);
  ushort* wguT  = (ushort*)take((size_t)ENUM_*NGUPAD*CDIM*2);
  ushort* dwT   = (ushort*)take((size_t)ENUM_*CDIM*IPAD*2);
  ushort* hbuf  = (ushort*)take((size_t)EGRP*CAP*IPAD*2);

  hipMemsetAsync(ctrl, 0, 64, stream);
  hipMemsetAsync(tokbuf, 0, (size_t)ENUM_*CAP*4, stream);
  hipMemsetAsync(wgtbuf, 0, (size_t)ENUM_*CAP*4, stream);
  hipMemsetAsync(out, 0, (size_t)out_size*sizeof(float), stream);

  k_cond<<<4, 256, 0, stream>>>(cond, gate_w, condlog);
  k_gate<<<T_TOK/16, 256, 0, stream>>>(x, gate_w, condlog, snr, cnt, entries, xb);
  k_tr_wgu<<<dim3(CDIM/32, NGUPAD/32, ENUM_), dim3(32,8), 0, stream>>>(wgu, wguT);
  k_tr_dwn<<<dim3(IPAD/32, CDIM/32, ENUM_), dim3(32,8), 0, stream>>>(wdn, dwT);
  k_select<<<ENUM_, 256, 0, stream>>>(cnt, entries, thresh);
  k_compact<<<dim3(64, ENUM_), 256, 0, stream>>>(cnt, entries, thresh, mcnt, tokbuf, wgtbuf);

  for (int g = 0; g < ENUM_/EGRP; ++g){
    k_gemm1<<<dim3(CAP/128, IPAD/64, EGRP), 256, 0, stream>>>(
        xb, wguT + (size_t)g*EGRP*NGUPAD*CDIM,
        tokbuf + (size_t)g*EGRP*CAP, mcnt + g*EGRP, hbuf);
    k_gemm2<<<dim3(CAP/128, CDIM/128, EGRP), 256, 0, stream>>>(
        hbuf, dwT + (size_t)g*EGRP*CDIM*IPAD,
        tokbuf + (size_t)g*EGRP*CAP, wgtbuf + (size_t)g*EGRP*CAP,
        mcnt + g*EGRP, out);
  }
}

// Round 3
// 1406.585 us; speedup vs baseline: 1.5849x; 1.1215x over previous
//
#include <hip/hip_runtime.h>
#include <hip/hip_bf16.h>
#include <stdint.h>

#define T_TOK 16384
#define CDIM  1024
#define ENUM_ 8
#define INTER_ 2730
#define IPAD  2752      // INTER padded to x64
#define NGU   5460
#define NGUPAD 5504     // 2*IPAD: [g | u] each padded to 2752
#define CAP   2560
#define EGRP  4         // experts per GEMM dispatch (blockIdx.z)

typedef __attribute__((ext_vector_type(8))) short short8;
typedef __attribute__((ext_vector_type(4))) float f32x4;
typedef unsigned long long u64;
typedef unsigned int u32;

static __device__ __forceinline__ ushort f2bf(float f){
  u32 u = __float_as_uint(f);
  u32 r = u + 0x7FFFu + ((u >> 16) & 1u);
  return (ushort)(r >> 16);
}

// async global->LDS, 16B per lane. LDS dest = wave-uniform base + lane*16.
static __device__ __forceinline__ void glds16(const void* g, void* l){
  __builtin_amdgcn_global_load_lds(
      (const __attribute__((address_space(1))) void*)g,
      (__attribute__((address_space(3))) void*)l, 16, 0, 0);
}

// ---------- weight transposes ----------
__global__ void k_tr_wgu(const float* __restrict__ wgu, ushort* __restrict__ wguT){
  __shared__ float tile[32][33];
  const int e = blockIdx.z;
  const int k0 = blockIdx.x*32, n0 = blockIdx.y*32;
  const float* src = wgu + (size_t)e*CDIM*NGU;
  ushort* dst = wguT + (size_t)e*NGUPAD*CDIM;
  const int tx = threadIdx.x, ty = threadIdx.y;
  #pragma unroll
  for (int r = ty; r < 32; r += 8){
    int n = n0 + tx;
    int j = (n < IPAD) ? n : n - (IPAD - INTER_);
    bool valid = (n < INTER_) || (n >= IPAD && j < NGU);
    tile[r][tx] = valid ? src[(size_t)(k0 + r)*NGU + j] : 0.f;
  }
  __syncthreads();
  #pragma unroll
  for (int r = ty; r < 32; r += 8)
    dst[(size_t)(n0 + r)*CDIM + k0 + tx] = f2bf(tile[tx][r]);
}

__global__ void k_tr_dwn(const float* __restrict__ dw, ushort* __restrict__ dwT){
  __shared__ float tile[32][33];
  const int e = blockIdx.z;
  const int k0 = blockIdx.x*32, n0 = blockIdx.y*32;
  const float* src = dw + (size_t)e*INTER_*CDIM;
  ushort* dst = dwT + (size_t)e*CDIM*IPAD;
  const int tx = threadIdx.x, ty = threadIdx.y;
  #pragma unroll
  for (int r = ty; r < 32; r += 8){
    int k = k0 + r;
    tile[r][tx] = (k < INTER_) ? src[(size_t)k*CDIM + n0 + tx] : 0.f;
  }
  __syncthreads();
  #pragma unroll
  for (int r = ty; r < 32; r += 8)
    dst[(size_t)(n0 + r)*IPAD + k0 + tx] = f2bf(tile[tx][r]);
}

// ---------- gating ----------
__global__ void k_cond(const float* __restrict__ cond, const float* __restrict__ gate_w,
                       float* __restrict__ condlog){
  const int b = blockIdx.x;
  const int wave = threadIdx.x >> 6, lane = threadIdx.x & 63;
  float a0 = 0.f, a1 = 0.f;
  for (int c = lane; c < CDIM; c += 64){
    float cv = cond[(size_t)b*CDIM + c];
    const float* g = gate_w + (size_t)(CDIM + c)*8;
    a0 += cv * g[2*wave]; a1 += cv * g[2*wave + 1];
  }
  #pragma unroll
  for (int off = 32; off; off >>= 1){
    a0 += __shfl_down(a0, off, 64);
    a1 += __shfl_down(a1, off, 64);
  }
  if (lane == 0){
    condlog[b*8 + 2*wave]     = a0;
    condlog[b*8 + 2*wave + 1] = a1;
  }
}

// Gate logits with LDS-cached transposed gate_w (gwT[e][c]; bank = c mod 32 =
// lane mod 32 -> 2-way = free). Fuses x -> bf16 conversion. Per-lane state is
// tiny (acc[8]) so no spill (round-2 lesson: 128-float arrays spill at VGPR 92).
__global__ __launch_bounds__(256) void k_gate(
    const float* __restrict__ x, const float* __restrict__ gate_w,
    const float* __restrict__ condlog, const float* __restrict__ snr,
    u32* __restrict__ cnt, u64* __restrict__ entries, ushort* __restrict__ xb){
  __shared__ float gwT[8*1024];
  const int tid = threadIdx.x;
  for (int idx = tid; idx < 8192; idx += 256){
    float v = gate_w[idx];                    // coalesced read, [c][e] flat
    gwT[(idx & 7)*1024 + (idx >> 3)] = v;     // transpose into [e][c] (once)
  }
  __syncthreads();
  const int wave = tid >> 6, lane = tid & 63;
  const int tbase = blockIdx.x*16 + wave*4;
  #pragma unroll 1
  for (int it = 0; it < 4; ++it){
    const int t = tbase + it;
    const int b = t >> 12;                    // N = 4096 tokens/batch
    float acc[8] = {0,0,0,0,0,0,0,0};
    #pragma unroll
    for (int i = 0; i < 16; ++i){
      const int c = lane + 64*i;
      float xv = x[(size_t)t*CDIM + c];
      xb[(size_t)t*CDIM + c] = f2bf(xv);
      #pragma unroll
      for (int e = 0; e < 8; ++e) acc[e] += xv * gwT[e*1024 + c];
    }
    #pragma unroll
    for (int e = 0; e < 8; ++e)
      #pragma unroll
      for (int off = 32; off; off >>= 1)
        acc[e] += __shfl_down(acc[e], off, 64);
    if (lane == 0){
      bool hn = snr[b] < 0.5f;
      float lg[8];
      #pragma unroll
      for (int e = 0; e < 8; ++e) lg[e] = acc[e] + condlog[b*8 + e];
      float mx = -1e30f;
      #pragma unroll
      for (int e = 0; e < 8; ++e) if (!(hn && e >= 2) && lg[e] > mx) mx = lg[e];
      float p[8]; float s = 0.f;
      #pragma unroll
      for (int e = 0; e < 8; ++e){ p[e] = (hn && e >= 2) ? 0.f : expf(lg[e] - mx); s += p[e]; }
      float inv = 1.f / s;
      #pragma unroll
      for (int e = 0; e < 8; ++e) p[e] *= inv;
      int i0 = 0;
      #pragma unroll
      for (int e = 1; e < 8; ++e) if (p[e] > p[i0]) i0 = e;
      int i1 = -1; float pv1 = -1.f;
      #pragma unroll
      for (int e = 0; e < 8; ++e) if (e != i0 && p[e] > pv1){ pv1 = p[e]; i1 = e; }
      float v0 = p[i0], v1 = pv1;
      float den = fmaxf(v0 + v1, 1e-12f);
      v0 /= den; v1 /= den;
      u32 flat0 = (u32)(t*2);
      u32 pos0 = atomicAdd(&cnt[i0], 1u);
      entries[(size_t)i0*T_TOK + pos0] =
          ((u64)__float_as_uint(v0) << 32) | (u64)(0xFFFFFFFFu - flat0);
      u32 pos1 = atomicAdd(&cnt[i1], 1u);
      entries[(size_t)i1*T_TOK + pos1] =
          ((u64)__float_as_uint(v1) << 32) | (u64)(0xFFFFFFFFu - (flat0 + 1u));
    }
  }
}

// ---------- capacity selection (exact top-k via unique 64b keys) ----------
__global__ void k_select(const u32* __restrict__ cnt, const u64* __restrict__ entries,
                         u64* __restrict__ thresh){
  const int e = blockIdx.x;
  const int n = (int)cnt[e];
  if (n <= CAP){ if (threadIdx.x == 0) thresh[e] = 0ull; return; }
  const u64* keys = entries + (size_t)e*T_TOK;
  __shared__ u32 hist[256];
  __shared__ u64 spfx;
  __shared__ int srem;
  u64 prefix = 0, pmask = 0;
  int rem = CAP;
  for (int d = 7; d >= 0; --d){
    const int sh = d*8;
    hist[threadIdx.x] = 0;
    __syncthreads();
    for (int i = threadIdx.x; i < n; i += 256){
      u64 k = keys[i];
      if ((k & pmask) == prefix)
        atomicAdd(&hist[(u32)((k >> sh) & 0xFFull)], 1u);
    }
    __syncthreads();
    if (threadIdx.x == 0){
      int c = 0, chosen = 0, nr = rem;
      for (int v = 255; v >= 0; --v){
        int nc = c + (int)hist[v];
        if (nc >= rem){ chosen = v; nr = rem - c; break; }
        c = nc;
      }
      spfx = prefix | ((u64)(u32)chosen << sh);
      srem = nr;
    }
    __syncthreads();
    prefix = spfx; rem = srem; pmask |= (0xFFull << sh);
  }
  if (threadIdx.x == 0) thresh[e] = prefix;
}

__global__ void k_compact(const u32* __restrict__ cnt, const u64* __restrict__ entries,
                          const u64* __restrict__ thresh, u32* __restrict__ mcnt,
                          int* __restrict__ tokbuf, float* __restrict__ wgtbuf){
  const int e = blockIdx.y;
  const int n = (int)cnt[e];
  const u64 th = thresh[e];
  const u64* keys = entries + (size_t)e*T_TOK;
  for (int i = blockIdx.x*256 + threadIdx.x; i < n; i += gridDim.x*256){
    u64 k = keys[i];
    if (k >= th){
      u32 pos = atomicAdd(&mcnt[e], 1u);
      u32 flat = 0xFFFFFFFFu - (u32)(k & 0xFFFFFFFFull);
      tokbuf[(size_t)e*CAP + pos] = (int)(flat >> 1);
      wgtbuf[(size_t)e*CAP + pos] = __uint_as_float((u32)(k >> 32));
    }
  }
}

// ---------- expert GEMMs, m97 structure ----------
__global__ __launch_bounds__(256) void k_gemm1(
    const ushort* __restrict__ xb, const ushort* __restrict__ wguT_g,
    const int* __restrict__ tok_g, const u32* __restrict__ mcnt_g,
    ushort* __restrict__ h_g){
  const int z = blockIdx.z;
  const int m_e = (int)mcnt_g[z];
  const int m0 = blockIdx.x * 128;
  if (m0 >= m_e) return;
  const ushort* wguT = wguT_g + (size_t)z*NGUPAD*CDIM;
  const int* tok = tok_g + (size_t)z*CAP;
  ushort* h = h_g + (size_t)z*CAP*IPAD;
  const int j0 = blockIdx.y * 64;

  __shared__ ushort As[128*32];
  __shared__ ushort Bg[64*32];
  __shared__ ushort Bu[64*32];
  const int tid = threadIdx.x;
  const int lane = tid & 63, wave = tid >> 6;
  const int wm = wave >> 1, wn = wave & 1;
  const int lm = lane & 15, quad = lane >> 4;

  const int af0 = tid*8, af1 = tid*8 + 2048;
  const ushort* ag0 = xb + (size_t)tok[m0 + (af0 >> 5)]*CDIM + (af0 & 31);
  const ushort* ag1 = xb + (size_t)tok[m0 + (af1 >> 5)]*CDIM + (af1 & 31);
  const int br = tid >> 2, bc = (tid & 3)*8;
  const ushort* bgp = wguT + (size_t)(j0 + br)*CDIM + bc;
  const ushort* bup = wguT + (size_t)(IPAD + j0 + br)*CDIM + bc;

  f32x4 accg[4][2], accu[4][2];
  #pragma unroll
  for (int i = 0; i < 4; ++i)
    #pragma unroll
    for (int j = 0; j < 2; ++j){
      accg[i][j] = (f32x4){0.f,0.f,0.f,0.f};
      accu[i][j] = (f32x4){0.f,0.f,0.f,0.f};
    }

  for (int k0 = 0; k0 < CDIM; k0 += 32){
    glds16(ag0 + k0, As + af0);
    glds16(ag1 + k0, As + af1);
    glds16(bgp + k0, Bg + tid*8);
    glds16(bup + k0, Bu + tid*8);
    __syncthreads();
    short8 a[4], vg[2], vu[2];
    #pragma unroll
    for (int mt = 0; mt < 4; ++mt)
      a[mt] = *(const short8*)(As + (wm*64 + mt*16 + lm)*32 + quad*8);
    #pragma unroll
    for (int nt = 0; nt < 2; ++nt){
      vg[nt] = *(const short8*)(Bg + (wn*32 + nt*16 + lm)*32 + quad*8);
      vu[nt] = *(const short8*)(Bu + (wn*32 + nt*16 + lm)*32 + quad*8);
    }
    __syncthreads();
    #pragma unroll
    for (int mt = 0; mt < 4; ++mt)
      #pragma unroll
      for (int nt = 0; nt < 2; ++nt){
        accg[mt][nt] = __builtin_amdgcn_mfma_f32_16x16x32_bf16(a[mt], vg[nt], accg[mt][nt], 0, 0, 0);
        accu[mt][nt] = __builtin_amdgcn_mfma_f32_16x16x32_bf16(a[mt], vu[nt], accu[mt][nt], 0, 0, 0);
      }
  }
  #pragma unroll
  for (int mt = 0; mt < 4; ++mt)
    #pragma unroll
    for (int nt = 0; nt < 2; ++nt)
      #pragma unroll
      for (int r = 0; r < 4; ++r){
        int row = m0 + wm*64 + mt*16 + quad*4 + r;
        int col = j0 + wn*32 + nt*16 + lm;
        float g = accg[mt][nt][r];
        float uu = accu[mt][nt][r];
        float sg = g / (1.f + __expf(-g));
        h[(size_t)row*IPAD + col] = f2bf(sg * uu);
      }
}

__global__ __launch_bounds__(256) void k_gemm2(
    const ushort* __restrict__ h_g, const ushort* __restrict__ dwT_g,
    const int* __restrict__ tok_g, const float* __restrict__ wgt_g,
    const u32* __restrict__ mcnt_g, float* __restrict__ out){
  const int z = blockIdx.z;
  const int m_e = (int)mcnt_g[z];
  const int m0 = blockIdx.x * 128;
  if (m0 >= m_e) return;
  const ushort* h = h_g + (size_t)z*CAP*IPAD;
  const ushort* dwT = dwT_g + (size_t)z*CDIM*IPAD;
  const int* tok = tok_g + (size_t)z*CAP;
  const float* wgt = wgt_g + (size_t)z*CAP;
  const int n0 = blockIdx.y * 128;

  __shared__ ushort As[128*32];
  __shared__ ushort Bs[128*32];
  const int tid = threadIdx.x;
  const int lane = tid & 63, wave = tid >> 6;
  const int wm = wave >> 1, wn = wave & 1;
  const int lm = lane & 15, quad = lane >> 4;

  const int af0 = tid*8, af1 = tid*8 + 2048;
  const ushort* ap0 = h + (size_t)(m0 + (af0 >> 5))*IPAD + (af0 & 31);
  const ushort* ap1 = h + (size_t)(m0 + (af1 >> 5))*IPAD + (af1 & 31);
  const ushort* bp0 = dwT + (size_t)(n0 + (af0 >> 5))*IPAD + (af0 & 31);
  const ushort* bp1 = dwT + (size_t)(n0 + (af1 >> 5))*IPAD + (af1 & 31);

  f32x4 acc[4][4];
  #pragma unroll
  for (int i = 0; i < 4; ++i)
    #pragma unroll
    for (int j = 0; j < 4; ++j) acc[i][j] = (f32x4){0.f,0.f,0.f,0.f};

  for (int k0 = 0; k0 < IPAD; k0 += 32){
    glds16(ap0 + k0, As + af0);
    glds16(ap1 + k0, As + af1);
    glds16(bp0 + k0, Bs + af0);
    glds16(bp1 + k0, Bs + af1);
    __syncthreads();
    short8 a[4], b[4];
    #pragma unroll
    for (int mt = 0; mt < 4; ++mt)
      a[mt] = *(const short8*)(As + (wm*64 + mt*16 + lm)*32 + quad*8);
    #pragma unroll
    for (int nt = 0; nt < 4; ++nt)
      b[nt] = *(const short8*)(Bs + (wn*64 + nt*16 + lm)*32 + quad*8);
    __syncthreads();
    #pragma unroll
    for (int mt = 0; mt < 4; ++mt)
      #pragma unroll
      for (int nt = 0; nt < 4; ++nt)
        acc[mt][nt] = __builtin_amdgcn_mfma_f32_16x16x32_bf16(a[mt], b[nt], acc[mt][nt], 0, 0, 0);
  }
  #pragma unroll
  for (int mt = 0; mt < 4; ++mt)
    #pragma unroll
    for (int r = 0; r < 4; ++r){
      int row = m0 + wm*64 + mt*16 + quad*4 + r;
      float w = wgt[row];                       // 0 for padded slots
      float* orow = out + (size_t)tok[row]*CDIM;
      #pragma unroll
      for (int nt = 0; nt < 4; ++nt){
        int col = n0 + wn*64 + nt*16 + lm;
        atomicAdd(orow + col, w * acc[mt][nt][r]);
      }
    }
}

extern "C" void kernel_launch(void* const* d_in, const int* in_sizes, int n_in,
                              void* d_out, int out_size, void* d_ws, size_t ws_size,
                              hipStream_t stream){
  const float* x      = (const float*)d_in[0];
  const float* cond   = (const float*)d_in[1];
  const float* snr    = (const float*)d_in[2];
  const float* gate_w = (const float*)d_in[3];
  const float* wgu    = (const float*)d_in[4];
  const float* wdn    = (const float*)d_in[5];
  float* out = (float*)d_out;
  (void)in_sizes; (void)n_in; (void)ws_size;

  char* ws = (char*)d_ws;
  size_t off = 0;
  auto take = [&](size_t bytes) -> char* {
    char* p = ws + off;
    off += (bytes + 255) & ~(size_t)255;
    return p;
  };
  u32* ctrl     = (u32*)take(256);
  u32* cnt      = ctrl;                      // 8 x u32
  u32* mcnt     = ctrl + 8;                  // 8 x u32
  float* condlog = (float*)(ctrl + 16);      // 32 x f32 @ byte 64
  u64* thresh   = (u64*)((char*)ctrl + 192); // 8 x u64
  u64* entries  = (u64*)take((size_t)ENUM_*T_TOK*8);
  int* tokbuf   = (int*)take((size_t)ENUM_*CAP*4);
  float* wgtbuf = (float*)take((size_t)ENUM_*CAP*4);
  ushort* xb    = (ushort*)take((size_t)T_TOK*CDIM*2);
  ushort* wguT  = (ushort*)take((size_t)ENUM_*NGUPAD*CDIM*2);
  ushort* dwT   = (ushort*)take((size_t)ENUM_*CDIM*IPAD*2);
  ushort* hbuf  = (ushort*)take((size_t)EGRP*CAP*IPAD*2);

  hipMemsetAsync(ctrl, 0, 64, stream);
  hipMemsetAsync(tokbuf, 0, (size_t)ENUM_*CAP*4, stream);
  hipMemsetAsync(wgtbuf, 0, (size_t)ENUM_*CAP*4, stream);
  hipMemsetAsync(out, 0, (size_t)out_size*sizeof(float), stream);

  k_cond<<<4, 256, 0, stream>>>(cond, gate_w, condlog);
  k_gate<<<T_TOK/16, 256, 0, stream>>>(x, gate_w, condlog, snr, cnt, entries, xb);
  k_tr_wgu<<<dim3(CDIM/32, NGUPAD/32, ENUM_), dim3(32,8), 0, stream>>>(wgu, wguT);
  k_tr_dwn<<<dim3(IPAD/32, CDIM/32, ENUM_), dim3(32,8), 0, stream>>>(wdn, dwT);
  k_select<<<ENUM_, 256, 0, stream>>>(cnt, entries, thresh);
  k_compact<<<dim3(64, ENUM_), 256, 0, stream>>>(cnt, entries, thresh, mcnt, tokbuf, wgtbuf);

  for (int g = 0; g < ENUM_/EGRP; ++g){
    k_gemm1<<<dim3(CAP/128, IPAD/64, EGRP), 256, 0, stream>>>(
        xb, wguT + (size_t)g*EGRP*NGUPAD*CDIM,
        tokbuf + (size_t)g*EGRP*CAP, mcnt + g*EGRP, hbuf);
    k_gemm2<<<dim3(CAP/128, CDIM/128, EGRP), 256, 0, stream>>>(
        hbuf, dwT + (size_t)g*EGRP*CDIM*IPAD,
        tokbuf + (size_t)g*EGRP*CAP, wgtbuf + (size_t)g*EGRP*CAP,
        mcnt + g*EGRP, out);
  }
}